// Round 1
// baseline (211.148 us; speedup 1.0000x reference)
//
#include <hip/hip_runtime.h>

typedef unsigned short u16;
typedef __bf16 bf16x8 __attribute__((ext_vector_type(8)));
typedef float f32x4 __attribute__((ext_vector_type(4)));
typedef u16 u16x8 __attribute__((ext_vector_type(8)));

#define NUM_HEADS 16
#define DHEAD 64
#define HIDDEN 1024
#define BATCH 4
#define SEQ 1024

__device__ __forceinline__ u16 f2bf(float x) {
  unsigned u = __float_as_uint(x);
  u = u + 0x7FFFu + ((u >> 16) & 1u);
  return (u16)(u >> 16);
}
__device__ __forceinline__ float bf2f(u16 b) {
  return __uint_as_float(((unsigned)b) << 16);
}

// async global->LDS, 16B per lane. LDS dest = wave-uniform base + lane*16.
__device__ __forceinline__ void async16(u16* lds, const u16* g) {
  __builtin_amdgcn_global_load_lds(
      (const __attribute__((address_space(1))) void*)g,
      (__attribute__((address_space(3))) void*)lds, 16, 0, 0);
}

// ---------------- prep: fp32 -> bf16 (x8 per thread) ----------------
__global__ void k_cvt(const float* __restrict__ in, u16* __restrict__ out, int n8) {
  int i = blockIdx.x * 256 + threadIdx.x;
  if (i >= n8) return;
  float4 a = ((const float4*)in)[i * 2];
  float4 b = ((const float4*)in)[i * 2 + 1];
  u16x8 v;
  v[0] = f2bf(a.x); v[1] = f2bf(a.y); v[2] = f2bf(a.z); v[3] = f2bf(a.w);
  v[4] = f2bf(b.x); v[5] = f2bf(b.y); v[6] = f2bf(b.z); v[7] = f2bf(b.w);
  *(u16x8*)&out[(size_t)i * 8] = v;
}

// ---------------- prep: W [K][N] fp32 -> Wt [N][K] bf16 ----------------
__global__ void k_wtrans(const float* __restrict__ Wq, const float* __restrict__ Wk,
                         const float* __restrict__ Wv, u16* __restrict__ Wt) {
  __shared__ float tile[64][65];
  const float* W = (blockIdx.z == 0) ? Wq : (blockIdx.z == 1) ? Wk : Wv;
  u16* out = Wt + (size_t)blockIdx.z * HIDDEN * HIDDEN;
  int k0 = blockIdx.y * 64, n0 = blockIdx.x * 64;
  int tid = threadIdx.x;
  int r = tid >> 6, c = tid & 63;
#pragma unroll
  for (int i = 0; i < 16; ++i)
    tile[i * 4 + r][c] = W[(size_t)(k0 + i * 4 + r) * HIDDEN + n0 + c];
  __syncthreads();
#pragma unroll
  for (int i = 0; i < 16; ++i)
    out[(size_t)(n0 + i * 4 + r) * HIDDEN + k0 + c] = f2bf(tile[c][i * 4 + r]);
}

// ---------------- prep: mask -> bf16 adder + tile flags ----------------
__global__ void k_mask(const float* __restrict__ mask, u16* __restrict__ adder,
                       int* __restrict__ flags) {
  int tt = blockIdx.x, ft = blockIdx.y, b = blockIdx.z;
  int tid = threadIdx.x;
  __shared__ int sflag;
  if (tid == 0) sflag = 0;
  __syncthreads();
  int any = 0;
  size_t base = ((size_t)b * SEQ + ft * 128) * SEQ + tt * 128;
  for (int i = 0; i < 64; ++i) {
    int idx = i * 256 + tid;
    int r = idx >> 7, c = idx & 127;
    float v = mask[base + (size_t)r * SEQ + c];
    any |= (v != 1.0f);
    adder[base + (size_t)r * SEQ + c] = f2bf((1.0f - v) * -10000.0f);
  }
  if (any) sflag = 1;
  __syncthreads();
  if (tid == 0) flags[(b * 8 + ft) * 8 + tt] = sflag;
}

// ---------------- QKV GEMM: C = X @ W + b, 128x128 tile, BK=64 ----------------
// z=0: Q -> Qh[B,H,F,64]; z=1: K -> Kh[B,H,T,64]; z=2: V -> Vt[B,H,64,T]
__global__ __launch_bounds__(256) void k_gemm(
    const u16* __restrict__ Af, const u16* __restrict__ At,
    const u16* __restrict__ Wt,
    const float* __restrict__ bq, const float* __restrict__ bk, const float* __restrict__ bv,
    u16* __restrict__ Qh, u16* __restrict__ Kh, u16* __restrict__ Vt) {
  __shared__ u16 sA[128 * 64];
  __shared__ u16 sB[128 * 64];
  int which = blockIdx.z;
  const u16* A = (which == 0) ? Af : At;
  const u16* B = Wt + (size_t)which * HIDDEN * HIDDEN;
  const float* bias = (which == 0) ? bq : (which == 1) ? bk : bv;
  int m0 = blockIdx.y * 128, n0 = blockIdx.x * 128;
  int tid = threadIdx.x, w = tid >> 6, lane = tid & 63;
  int wr = w >> 1, wc = w & 1;
  int g = lane >> 4, cc = lane & 15;

  f32x4 acc[4][4] = {};

  int sx[4], srow[4], scol[4];
#pragma unroll
  for (int i = 0; i < 4; ++i) {
    int ch = w * 4 + i;
    int x = ch * 1024 + lane * 16;
    int row = x >> 7;
    int colb = (x & 127) ^ ((row & 7) << 4);  // pre-swizzled source (rule #21)
    sx[i] = ch * 512;
    srow[i] = row;
    scol[i] = colb >> 1;
  }

  for (int kt = 0; kt < HIDDEN / 64; ++kt) {
    __syncthreads();
#pragma unroll
    for (int i = 0; i < 4; ++i) {
      async16(&sA[sx[i]], A + (size_t)(m0 + srow[i]) * HIDDEN + kt * 64 + scol[i]);
      async16(&sB[sx[i]], B + (size_t)(n0 + srow[i]) * HIDDEN + kt * 64 + scol[i]);
    }
    asm volatile("s_waitcnt vmcnt(0)" ::: "memory");
    __syncthreads();
#pragma unroll
    for (int kk = 0; kk < 2; ++kk) {
      bf16x8 af[4], bfr[4];
#pragma unroll
      for (int mf = 0; mf < 4; ++mf) {
        int row = wr * 64 + mf * 16 + cc;
        int colb = (kk * 64 + (g << 4)) ^ ((row & 7) << 4);
        af[mf] = *(const bf16x8*)&sA[(row * 128 + colb) >> 1];
      }
#pragma unroll
      for (int nf = 0; nf < 4; ++nf) {
        int row = wc * 64 + nf * 16 + cc;
        int colb = (kk * 64 + (g << 4)) ^ ((row & 7) << 4);
        bfr[nf] = *(const bf16x8*)&sB[(row * 128 + colb) >> 1];
      }
#pragma unroll
      for (int mf = 0; mf < 4; ++mf)
#pragma unroll
        for (int nf = 0; nf < 4; ++nf)
          acc[mf][nf] = __builtin_amdgcn_mfma_f32_16x16x32_bf16(af[mf], bfr[nf], acc[mf][nf], 0, 0, 0);
    }
  }

#pragma unroll
  for (int mf = 0; mf < 4; ++mf) {
#pragma unroll
    for (int nf = 0; nf < 4; ++nf) {
      int n = n0 + wc * 64 + nf * 16 + cc;
      float bval = bias[n];
      int h = n >> 6, d = n & 63;
#pragma unroll
      for (int r = 0; r < 4; ++r) {
        int m = m0 + wr * 64 + mf * 16 + g * 4 + r;
        int b = m >> 10, s = m & 1023;
        u16 o = f2bf(acc[mf][nf][r] + bval);
        if (which == 0)
          Qh[((((size_t)b * NUM_HEADS + h) * SEQ + s) << 6) + d] = o;
        else if (which == 1)
          Kh[((((size_t)b * NUM_HEADS + h) * SEQ + s) << 6) + d] = o;
        else
          Vt[(((size_t)b * NUM_HEADS + h) * 64 + d) * SEQ + s] = o;
      }
    }
  }
}

// ---------------- fused attention: 2-pass online softmax per (b,h,128-f-tile) ----------------
__global__ __launch_bounds__(256) void k_attn(
    const u16* __restrict__ Qh, const u16* __restrict__ Kh, const u16* __restrict__ Vt,
    const u16* __restrict__ adder, const int* __restrict__ flags,
    float* __restrict__ ctx, float* __restrict__ probs) {
  __shared__ u16 sQ[128 * 64];   // 16 KB, rows 128 B, swizzled
  __shared__ u16 sK[128 * 64];   // 16 KB
  __shared__ u16 sV[64 * 128];   // 16 KB, rows 256 B (V^T slice), swizzled
  __shared__ u16 sP[128 * 128];  // 32 KB, rows 256 B, swizzled
  int ft = blockIdx.x, h = blockIdx.y, b = blockIdx.z;
  int f0 = ft * 128;
  int bh = b * NUM_HEADS + h;
  const u16* Qg = Qh + ((size_t)bh * SEQ + f0) * 64;
  const u16* Kg = Kh + (size_t)bh * SEQ * 64;
  const u16* Vg = Vt + (size_t)bh * 64 * SEQ;
  int tid = threadIdx.x, w = tid >> 6, lane = tid & 63;
  int g = lane >> 4, cc = lane & 15;
  const int fbase = w * 32;

  int sx[4], srow7[4], scol7[4], srow8[4], scol8[4];
#pragma unroll
  for (int i = 0; i < 4; ++i) {
    int ch = w * 4 + i;
    int x = ch * 1024 + lane * 16;
    sx[i] = ch * 512;
    int r7 = x >> 7;
    int c7 = (x & 127) ^ ((r7 & 7) << 4);
    srow7[i] = r7; scol7[i] = c7 >> 1;
    int r8 = x >> 8;
    int c8 = (x & 255) ^ ((r8 & 7) << 4);
    srow8[i] = r8; scol8[i] = c8 >> 1;
  }

#pragma unroll
  for (int i = 0; i < 4; ++i)
    async16(&sQ[sx[i]], Qg + (size_t)srow7[i] * 64 + scol7[i]);

  float m_run[8], l_run[8];
#pragma unroll
  for (int i = 0; i < 8; ++i) { m_run[i] = -3.0e38f; l_run[i] = 0.0f; }

  // ---- pass 1: online (m,l) ----
  for (int tt = 0; tt < 8; ++tt) {
    __syncthreads();
#pragma unroll
    for (int i = 0; i < 4; ++i)
      async16(&sK[sx[i]], Kg + (size_t)(tt * 128 + srow7[i]) * 64 + scol7[i]);
    asm volatile("s_waitcnt vmcnt(0)" ::: "memory");
    __syncthreads();

    f32x4 s[2][8] = {};
#pragma unroll
    for (int kk = 0; kk < 2; ++kk) {
      bf16x8 aq[2], bk8[8];
#pragma unroll
      for (int mf = 0; mf < 2; ++mf) {
        int row = fbase + mf * 16 + cc;
        int colb = (kk * 64 + (g << 4)) ^ ((row & 7) << 4);
        aq[mf] = *(const bf16x8*)&sQ[(row * 128 + colb) >> 1];
      }
#pragma unroll
      for (int nf = 0; nf < 8; ++nf) {
        int row = nf * 16 + cc;
        int colb = (kk * 64 + (g << 4)) ^ ((row & 7) << 4);
        bk8[nf] = *(const bf16x8*)&sK[(row * 128 + colb) >> 1];
      }
#pragma unroll
      for (int mf = 0; mf < 2; ++mf)
#pragma unroll
        for (int nf = 0; nf < 8; ++nf)
          s[mf][nf] = __builtin_amdgcn_mfma_f32_16x16x32_bf16(aq[mf], bk8[nf], s[mf][nf], 0, 0, 0);
    }
    int flg = flags[(b * 8 + ft) * 8 + tt];
#pragma unroll
    for (int mf = 0; mf < 2; ++mf)
#pragma unroll
      for (int nf = 0; nf < 8; ++nf)
#pragma unroll
        for (int r = 0; r < 4; ++r) s[mf][nf][r] *= 0.125f;
    if (flg) {
      for (int mf = 0; mf < 2; ++mf)
        for (int nf = 0; nf < 8; ++nf)
          for (int r = 0; r < 4; ++r) {
            int frow = f0 + fbase + mf * 16 + g * 4 + r;
            int tcol = tt * 128 + nf * 16 + cc;
            s[mf][nf][r] += bf2f(adder[((size_t)b * SEQ + frow) * SEQ + tcol]);
          }
    }
#pragma unroll
    for (int mf = 0; mf < 2; ++mf)
#pragma unroll
      for (int r = 0; r < 4; ++r) {
        float tmax = s[mf][0][r];
#pragma unroll
        for (int nf = 1; nf < 8; ++nf) tmax = fmaxf(tmax, s[mf][nf][r]);
        tmax = fmaxf(tmax, __shfl_xor(tmax, 1, 16));
        tmax = fmaxf(tmax, __shfl_xor(tmax, 2, 16));
        tmax = fmaxf(tmax, __shfl_xor(tmax, 4, 16));
        tmax = fmaxf(tmax, __shfl_xor(tmax, 8, 16));
        int idx = mf * 4 + r;
        float mnew = fmaxf(m_run[idx], tmax);
        float sum = 0.f;
#pragma unroll
        for (int nf = 0; nf < 8; ++nf) sum += __expf(s[mf][nf][r] - mnew);
        sum += __shfl_xor(sum, 1, 16);
        sum += __shfl_xor(sum, 2, 16);
        sum += __shfl_xor(sum, 4, 16);
        sum += __shfl_xor(sum, 8, 16);
        l_run[idx] = l_run[idx] * __expf(m_run[idx] - mnew) + sum;
        m_run[idx] = mnew;
      }
  }

  float inv_l[8];
#pragma unroll
  for (int i = 0; i < 8; ++i) inv_l[i] = 1.0f / l_run[i];

  f32x4 accO[2][4] = {};

  // ---- pass 2: recompute S, write probs, accumulate ctx ----
  for (int tt = 0; tt < 8; ++tt) {
    __syncthreads();
#pragma unroll
    for (int i = 0; i < 4; ++i) {
      async16(&sK[sx[i]], Kg + (size_t)(tt * 128 + srow7[i]) * 64 + scol7[i]);
      async16(&sV[sx[i]], Vg + (size_t)srow8[i] * SEQ + tt * 128 + scol8[i]);
    }
    asm volatile("s_waitcnt vmcnt(0)" ::: "memory");
    __syncthreads();

    f32x4 s[2][8] = {};
#pragma unroll
    for (int kk = 0; kk < 2; ++kk) {
      bf16x8 aq[2], bk8[8];
#pragma unroll
      for (int mf = 0; mf < 2; ++mf) {
        int row = fbase + mf * 16 + cc;
        int colb = (kk * 64 + (g << 4)) ^ ((row & 7) << 4);
        aq[mf] = *(const bf16x8*)&sQ[(row * 128 + colb) >> 1];
      }
#pragma unroll
      for (int nf = 0; nf < 8; ++nf) {
        int row = nf * 16 + cc;
        int colb = (kk * 64 + (g << 4)) ^ ((row & 7) << 4);
        bk8[nf] = *(const bf16x8*)&sK[(row * 128 + colb) >> 1];
      }
#pragma unroll
      for (int mf = 0; mf < 2; ++mf)
#pragma unroll
        for (int nf = 0; nf < 8; ++nf)
          s[mf][nf] = __builtin_amdgcn_mfma_f32_16x16x32_bf16(aq[mf], bk8[nf], s[mf][nf], 0, 0, 0);
    }
    int flg = flags[(b * 8 + ft) * 8 + tt];
#pragma unroll
    for (int mf = 0; mf < 2; ++mf)
#pragma unroll
      for (int nf = 0; nf < 8; ++nf)
#pragma unroll
        for (int r = 0; r < 4; ++r) s[mf][nf][r] *= 0.125f;
    if (flg) {
      for (int mf = 0; mf < 2; ++mf)
        for (int nf = 0; nf < 8; ++nf)
          for (int r = 0; r < 4; ++r) {
            int frow = f0 + fbase + mf * 16 + g * 4 + r;
            int tcol = tt * 128 + nf * 16 + cc;
            s[mf][nf][r] += bf2f(adder[((size_t)b * SEQ + frow) * SEQ + tcol]);
          }
    }
#pragma unroll
    for (int mf = 0; mf < 2; ++mf)
#pragma unroll
      for (int nf = 0; nf < 8; ++nf)
#pragma unroll
        for (int r = 0; r < 4; ++r) {
          int idx = mf * 4 + r;
          float p = __expf(s[mf][nf][r] - m_run[idx]) * inv_l[idx];
          int frow = fbase + mf * 16 + g * 4 + r;
          int tcol = nf * 16 + cc;
          probs[(((size_t)bh * SEQ) + f0 + frow) * SEQ + tt * 128 + tcol] = p;
          sP[(frow * 256 + ((tcol * 2) ^ ((frow & 7) << 4))) >> 1] = f2bf(p);
        }
#pragma unroll
    for (int ks = 0; ks < 4; ++ks) {
      bf16x8 ap[2], bv8[4];
#pragma unroll
      for (int mf = 0; mf < 2; ++mf) {
        int row = fbase + mf * 16 + cc;
        int colb = (ks * 64 + (g << 4)) ^ ((row & 7) << 4);
        ap[mf] = *(const bf16x8*)&sP[(row * 256 + colb) >> 1];
      }
#pragma unroll
      for (int nf = 0; nf < 4; ++nf) {
        int row = nf * 16 + cc;
        int colb = (ks * 64 + (g << 4)) ^ ((row & 7) << 4);
        bv8[nf] = *(const bf16x8*)&sV[(row * 256 + colb) >> 1];
      }
#pragma unroll
      for (int mf = 0; mf < 2; ++mf)
#pragma unroll
        for (int nf = 0; nf < 4; ++nf)
          accO[mf][nf] = __builtin_amdgcn_mfma_f32_16x16x32_bf16(ap[mf], bv8[nf], accO[mf][nf], 0, 0, 0);
    }
  }

#pragma unroll
  for (int mf = 0; mf < 2; ++mf)
#pragma unroll
    for (int nf = 0; nf < 4; ++nf)
#pragma unroll
      for (int r = 0; r < 4; ++r) {
        int frow = fbase + mf * 16 + g * 4 + r;
        int d = nf * 16 + cc;
        ctx[((size_t)b * SEQ + f0 + frow) * HIDDEN + h * 64 + d] = accO[mf][nf][r];
      }
}

extern "C" void kernel_launch(void* const* d_in, const int* in_sizes, int n_in,
                              void* d_out, int out_size, void* d_ws, size_t ws_size,
                              hipStream_t stream) {
  const float* from = (const float*)d_in[0];
  const float* to   = (const float*)d_in[1];
  const float* mask = (const float*)d_in[2];
  const float* Wq   = (const float*)d_in[3];
  const float* bq   = (const float*)d_in[4];
  const float* Wk   = (const float*)d_in[5];
  const float* bk   = (const float*)d_in[6];
  const float* Wv   = (const float*)d_in[7];
  const float* bv   = (const float*)d_in[8];

  char* ws = (char*)d_ws;
  u16* Af    = (u16*)(ws);                    // 8,388,608 B
  u16* At    = (u16*)(ws + 8388608);          // 8,388,608
  u16* Wt    = (u16*)(ws + 16777216);         // 6,291,456
  u16* adder = (u16*)(ws + 23068672);         // 8,388,608
  int* flags = (int*)(ws + 31457280);         // 1,024
  u16* Qh    = (u16*)(ws + 31458304);         // 8,388,608
  u16* Kh    = (u16*)(ws + 39846912);         // 8,388,608
  u16* Vt    = (u16*)(ws + 48235520);         // 8,388,608  (end ~54 MB)

  float* ctx = (float*)d_out;
  float* probs = ctx + (size_t)BATCH * SEQ * HIDDEN;

  k_cvt<<<2048, 256, 0, stream>>>(from, Af, 524288);
  k_cvt<<<2048, 256, 0, stream>>>(to, At, 524288);
  k_wtrans<<<dim3(16, 16, 3), 256, 0, stream>>>(Wq, Wk, Wv, Wt);
  k_mask<<<dim3(8, 8, 4), 256, 0, stream>>>(mask, adder, flags);
  k_gemm<<<dim3(8, 32, 3), 256, 0, stream>>>(Af, At, Wt, bq, bk, bv, Qh, Kh, Vt);
  k_attn<<<dim3(8, 16, 4), 256, 0, stream>>>(Qh, Kh, Vt, adder, flags, ctx, probs);
}